// Round 8
// baseline (769.120 us; speedup 1.0000x reference)
//
#include <hip/hip_runtime.h>
#include <stdint.h>

#define AS1 __attribute__((address_space(1)))
#define AS3 __attribute__((address_space(3)))

typedef unsigned short US;
typedef __bf16 bf16x8 __attribute__((ext_vector_type(8)));
typedef float f32x4 __attribute__((ext_vector_type(4)));

static constexpr int Bsz = 16384;
static constexpr int DIN = 512;
static constexpr int DH  = 1024;
static constexpr int LDA = 2560;   // Ab row: [h(1024) | x(512) | s(1024)]
static constexpr int LDR = 1536;   // RH row: [r*h(1024) | x(512)]

__device__ __forceinline__ US f2bf(float f) {
  unsigned u = __float_as_uint(f);
  u += 0x7fffu + ((u >> 16) & 1u);          // RNE
  return (US)(u >> 16);
}
__device__ __forceinline__ float bf2f(US u) { return __uint_as_float(((unsigned)u) << 16); }
__device__ __forceinline__ float sigm(float x) { return 1.f / (1.f + __expf(-x)); }
__device__ __forceinline__ float tanh_f(float x) { return 1.f - 2.f / (1.f + __expf(2.f * x)); }

// R7 post-mortem: R1's loop (compiler-VISIBLE ds_reads + builtin s_barrier +
// builtin counted s_waitcnt) is the measured-best schedule of the session
// (1.0 cyc/KFLOP vs 1.2-1.3 for every inline-asm variant). Visible reads let
// the backend interleave lgkmcnt(4/3/1/0) per MFMA operand instead of my
// bulk lgkmcnt(0) drains. This file = R1's K-loop verbatim + fused s/r/z.
#define BARR  __builtin_amdgcn_s_barrier()
#define SB0   __builtin_amdgcn_sched_barrier(0)

// ---------- convert kernels ----------
__global__ void pack_A(const float* __restrict__ h, const float* __restrict__ x,
                       US* __restrict__ Ab, US* __restrict__ RHx) {
  const int total = Bsz * 384;              // 1536 cols / 4 per item
  for (int idx = blockIdx.x * blockDim.x + threadIdx.x; idx < total;
       idx += gridDim.x * blockDim.x) {
    int row = idx / 384;
    int c = (idx - row * 384) * 4;
    const float* src = (c < DH) ? (h + (size_t)row * DH + c)
                                : (x + (size_t)row * DIN + (c - DH));
    float4 v = *(const float4*)src;
    ushort4 o;
    o.x = f2bf(v.x); o.y = f2bf(v.y); o.z = f2bf(v.z); o.w = f2bf(v.w);
    *(ushort4*)(Ab + (size_t)row * LDA + c) = o;
    if (c >= DH) *(ushort4*)(RHx + (size_t)row * LDR + c) = o;
  }
}

struct WSlot { const float* src; US* dst; int n4; int ksh; int ld; int co; };
struct WBatch { WSlot s[11]; };
__global__ void conv_w(WBatch b) {
  WSlot sl = b.s[blockIdx.y];   // uniform per block
  const int mask = (1 << sl.ksh) - 1;
  for (int i = blockIdx.x * blockDim.x + threadIdx.x; i < sl.n4;
       i += gridDim.x * blockDim.x) {
    float4 v = *(const float4*)(sl.src + (size_t)i * 4);
    ushort4 o;
    o.x = f2bf(v.x); o.y = f2bf(v.y); o.z = f2bf(v.z); o.w = f2bf(v.w);
    int r = i >> sl.ksh;
    int cc = (i & mask) * 4;
    *(ushort4*)(sl.dst + (size_t)r * sl.ld + sl.co + cc) = o;
  }
}

// ---------- 256x256 8-phase GEMM (R1's verbatim loop), fused epilogue -------
// 8 waves (2Mx4N), BK=64, dbuf LDS. Staging: A one tile ahead (ph0/ph1 ->
// buf^1, always-safe), B two tiles ahead (ph2/ph3 -> buf[cur], Bs[cur] dead
// after ph1-end barrier). Boundary: builtin s_waitcnt vmcnt(4) — at the wait,
// outstanding = B(t+1)(4, from t-1) + A(t+1)(4) + B(t+2)(4) = 12; vmcnt(4)
// retires B(t+1)+A(t+1) => tile t+1 resident, B(t+2) stays in flight.
// Compiler-visible LDS reads: backend schedules fine-grained lgkmcnt.
//
// EPI: 0 = fused s/r/z (gate = nIdx>>2)   3 = htilde(tanh)   4 = T + combine
template <int EPI, int NBLK>
__global__ __launch_bounds__(512, 2) void gemm8(
    const US* __restrict__ A, int lda,
    const US* __restrict__ W, int ldw, int nt,
    const float* __restrict__ bias0, const float* __restrict__ bias1,
    const float* __restrict__ bias2,
    const void* aux0, const void* aux1, const void* aux2,
    void* out0, int ldo0, void* out1, void* out2) {
  __shared__ __align__(16) US As[2][256 * 64];
  __shared__ __align__(16) US Bs[2][256 * 64];

  const int tid  = threadIdx.x;
  const int lane = tid & 63;
  const int w    = tid >> 6;          // wave 0..7
  const int wr   = w >> 2;            // m half (128 rows)
  const int wc   = w & 3;             // n quarter (64 cols)
  const int quad = lane >> 4, l15 = lane & 15;
  const int sw8  = l15 & 7;
  const int lrow = lane >> 3;
  const int scc  = (lane & 7) ^ (lrow & 7);

  // XCD-aware bijective swizzle: XCD c owns m-blocks [c*8, c*8+8) x all NBLK
  // n-peers -> A tiles fetched ~once per XCD L2.
  const int p = blockIdx.x;
  const int c = p & 7, q = p >> 3;
  const int nIdx = q % NBLK, mIdx = c * 8 + q / NBLK;
  const int mBase = mIdx * 256, nBase = nIdx * 256;

  f32x4 acc[8][4];
#pragma unroll
  for (int i = 0; i < 8; i++)
#pragma unroll
    for (int j = 0; j < 4; j++) acc[i][j] = f32x4{0.f, 0.f, 0.f, 0.f};

  const size_t aRowS = (size_t)(mBase + w * 8 + lrow) * lda;
  const size_t wRowS = (size_t)(nBase + w * 8 + lrow) * ldw;
  const int sccOff = scc * 8;

#define STAGE_A(d, hh, co)                                                       \
  { const US* g = A + aRowS + (size_t)(hh) * 128 * lda + (co) + sccOff;          \
    __builtin_amdgcn_global_load_lds((AS1 const void*)g,                         \
        (AS3 void*)&As[d][((hh)*128 + w * 8) * 64], 16, 0, 0);                   \
    __builtin_amdgcn_global_load_lds((AS1 const void*)(g + (size_t)64 * lda),    \
        (AS3 void*)&As[d][((hh)*128 + 64 + w * 8) * 64], 16, 0, 0); }
#define STAGE_B(d, hh, co)                                                       \
  { const US* g = W + wRowS + (size_t)(hh) * 128 * ldw + (co) + sccOff;          \
    __builtin_amdgcn_global_load_lds((AS1 const void*)g,                         \
        (AS3 void*)&Bs[d][((hh)*128 + w * 8) * 64], 16, 0, 0);                   \
    __builtin_amdgcn_global_load_lds((AS1 const void*)(g + (size_t)64 * ldw),    \
        (AS3 void*)&Bs[d][((hh)*128 + 64 + w * 8) * 64], 16, 0, 0); }

#define READ_A(mh)                                                               \
  _Pragma("unroll")                                                              \
  for (int i = 0; i < 4; ++i)                                                    \
    _Pragma("unroll")                                                            \
    for (int ks = 0; ks < 2; ++ks)                                               \
      af[i][ks] = *(const bf16x8*)&As[cur][(wr * 128 + (mh)*64 + i * 16 + l15)   \
                                          * 64 + (((ks * 4 + quad) ^ sw8) * 8)];
#define READ_B(BSET, nh)                                                         \
  _Pragma("unroll")                                                              \
  for (int j = 0; j < 2; ++j)                                                    \
    _Pragma("unroll")                                                            \
    for (int ks = 0; ks < 2; ++ks)                                               \
      BSET[j][ks] = *(const bf16x8*)&Bs[cur][(wc * 64 + (nh)*32 + j * 16 + l15)  \
                                            * 64 + (((ks * 4 + quad) ^ sw8) * 8)];
#define MFMA_Q(mh, BSET, nh)                                                     \
  _Pragma("unroll")                                                              \
  for (int ks = 0; ks < 2; ++ks)                                                 \
    _Pragma("unroll")                                                            \
    for (int i = 0; i < 4; ++i)                                                  \
      _Pragma("unroll")                                                          \
      for (int j = 0; j < 2; ++j)                                                \
        acc[(mh)*4 + i][(nh)*2 + j] = __builtin_amdgcn_mfma_f32_16x16x32_bf16(   \
            af[i][ks], BSET[j][ks], acc[(mh)*4 + i][(nh)*2 + j], 0, 0, 0);

  // ---- prologue: tile0 fully + B halves of tile1; retire tile0 only ----
  STAGE_A(0, 0, 0); STAGE_A(0, 1, 0); STAGE_B(0, 0, 0); STAGE_B(0, 1, 0);
  if (nt > 1) { STAGE_B(1, 0, 64); STAGE_B(1, 1, 64); }
  if (nt > 1) __builtin_amdgcn_s_waitcnt(0x0f74);   // vmcnt(4)
  else        __builtin_amdgcn_s_waitcnt(0x0f70);   // vmcnt(0)
  BARR;
  SB0;

  bf16x8 af[4][2], b0[2][2], b1[2][2];
  int cur = 0;

  for (int t = 0; t < nt; ++t, cur ^= 1) {
    const int nxt = cur ^ 1;
    const int co1 = (t + 1) * 64, co2 = (t + 2) * 64;
    // ---- phase 0: Q(m0,n0); prefetch A(t+1)h0 -> buf^1 ----
    READ_A(0);
    READ_B(b0, 0);
    if (t + 1 < nt) STAGE_A(nxt, 0, co1);
    BARR;
    __builtin_amdgcn_s_setprio(1);
    MFMA_Q(0, b0, 0);
    __builtin_amdgcn_s_setprio(0);
    BARR;
    // ---- phase 1: Q(m0,n1); prefetch A(t+1)h1 -> buf^1 ----
    READ_B(b1, 1);
    if (t + 1 < nt) STAGE_A(nxt, 1, co1);
    BARR;
    __builtin_amdgcn_s_setprio(1);
    MFMA_Q(0, b1, 1);
    __builtin_amdgcn_s_setprio(0);
    BARR;
    // ---- phase 2: Q(m1,n0); prefetch B(t+2)h0 -> buf[cur] (Bs dead) ----
    READ_A(1);
    if (t + 2 < nt) STAGE_B(cur, 0, co2);
    BARR;
    __builtin_amdgcn_s_setprio(1);
    MFMA_Q(1, b0, 0);
    __builtin_amdgcn_s_setprio(0);
    BARR;
    // ---- phase 3: Q(m1,n1); prefetch B(t+2)h1; boundary vmcnt(4) ----
    if (t + 2 < nt) STAGE_B(cur, 1, co2);
    BARR;
    __builtin_amdgcn_s_setprio(1);
    MFMA_Q(1, b1, 1);
    __builtin_amdgcn_s_setprio(0);
    if (t + 1 < nt) {
      if (t + 2 < nt) __builtin_amdgcn_s_waitcnt(0x0f74);  // vmcnt(4)
      else            __builtin_amdgcn_s_waitcnt(0x0f70);  // vmcnt(0) drain
      BARR;
      SB0;   // pin next tile's ds_reads behind the vmcnt guarantee
    }
  }
#undef STAGE_A
#undef STAGE_B
#undef READ_A
#undef READ_B
#undef MFMA_Q

  // epilogue: row = mBase+wr*128+im*16+quad*4+r ; col = nBase+wc*64+jn*16+l15
#pragma unroll
  for (int im = 0; im < 8; ++im) {
#pragma unroll
    for (int jn = 0; jn < 4; ++jn) {
      const int col = nBase + wc * 64 + jn * 16 + l15;
      if constexpr (EPI == 0) {
        const int g = nIdx >> 2;                 // 0=s 1=r 2=z (block-uniform)
        const int colg = col & 1023;
        const float* bp = (g == 0) ? bias0 : (g == 1) ? bias1 : bias2;
        const float bv = bp[colg];
        const float* delta = (const float*)aux0;
        const float* wst   = (const float*)aux1;
        const float* hp    = (const float*)aux2;
#pragma unroll
        for (int r = 0; r < 4; ++r) {
          const int row = mBase + wr * 128 + im * 16 + quad * 4 + r;
          float v = acc[im][jn][r] + bv;
          if (g == 0) {
            v += delta[row] * wst[colg];
            ((US*)out0)[(size_t)row * ldo0 + colg] = f2bf(tanh_f(v));
          } else if (g == 1) {
            float rr = sigm(v);
            ((US*)out1)[(size_t)row * LDR + colg] =
                f2bf(rr * hp[(size_t)row * DH + colg]);
          } else {
            ((US*)out2)[(size_t)row * DH + colg] = f2bf(sigm(v));
          }
        }
      } else if constexpr (EPI == 3) {
        const float bv = bias0[col];
#pragma unroll
        for (int r = 0; r < 4; ++r) {
          const int row = mBase + wr * 128 + im * 16 + quad * 4 + r;
          float v = acc[im][jn][r] + bv;
          ((US*)out0)[(size_t)row * ldo0 + col] = f2bf(tanh_f(v));
        }
      } else {
        const float bv = bias0[col];
        const float* hp = (const float*)aux0;   // pristine f32 h_prev
        const US* Zp = (const US*)aux1;         // z, stride DH
        const US* Hp = (const US*)aux2;         // htilde, stride DH
#pragma unroll
        for (int r = 0; r < 4; ++r) {
          const int row = mBase + wr * 128 + im * 16 + quad * 4 + r;
          float v = acc[im][jn][r] + bv;
          float T = sigm(v);
          size_t o = (size_t)row * DH + col;
          float z = bf2f(Zp[o]), ht = bf2f(Hp[o]);
          float h = hp[o];
          ((float*)out0)[(size_t)row * ldo0 + col] = (1.f - z) * (T * h) + z * ht;
        }
      }
    }
  }
}

extern "C" void kernel_launch(void* const* d_in, const int* in_sizes, int n_in,
                              void* d_out, int out_size, void* d_ws, size_t ws_size,
                              hipStream_t stream) {
  const float* x_t   = (const float*)d_in[0];
  const float* delta = (const float*)d_in[1];
  const float* h_prev= (const float*)d_in[2];
  const float* W_sh  = (const float*)d_in[3];
  const float* W_sx  = (const float*)d_in[4];
  const float* W_st  = (const float*)d_in[5];
  const float* b_s   = (const float*)d_in[6];
  const float* WTh   = (const float*)d_in[7];
  const float* WTx   = (const float*)d_in[8];
  const float* WTs   = (const float*)d_in[9];
  const float* b_T   = (const float*)d_in[10];
  const float* W_rh  = (const float*)d_in[11];
  const float* W_rx  = (const float*)d_in[12];
  const float* b_r   = (const float*)d_in[13];
  const float* W_zh  = (const float*)d_in[14];
  const float* W_zx  = (const float*)d_in[15];
  const float* b_z   = (const float*)d_in[16];
  const float* W_h   = (const float*)d_in[17];
  const float* W_x   = (const float*)d_in[18];
  const float* b_    = (const float*)d_in[19];
  float* out = (float*)d_out;

  char* ws = (char*)d_ws;
  US* Ab  = (US*)ws;              size_t off = (size_t)Bsz * LDA * 2;   // 80MB
  US* RH  = (US*)(ws + off);      off += (size_t)Bsz * LDR * 2;         // 48MB
  US* Zb  = (US*)(ws + off);      off += (size_t)Bsz * DH * 2;          // 32MB
  US* HTb = (US*)(ws + off);      off += (size_t)Bsz * DH * 2;          // 32MB
  US* bWsrz = (US*)(ws + off);    off += (size_t)3072 * 1536 * 2;       // 9MB
  US* bWT   = (US*)(ws + off);    off += (size_t)DH * 2560 * 2;         // 5MB
  US* bWh   = (US*)(ws + off);    off += (size_t)DH * 1536 * 2;         // 3MB

  // Stage 0: convert
  pack_A<<<dim3(8192), 256, 0, stream>>>(h_prev, x_t, Ab, RH);
  WBatch wb;
  const int n4h = DH * DH / 4, n4x = DH * DIN / 4;   // ksh: 1024->8, 512->7
  US* bWr = bWsrz + (size_t)1024 * 1536;
  US* bWz = bWsrz + (size_t)2048 * 1536;
  wb.s[0]  = {W_sh, bWsrz, n4h, 8, 1536, 0};
  wb.s[1]  = {W_sx, bWsrz, n4x, 7, 1536, 1024};
  wb.s[2]  = {W_rh, bWr,   n4h, 8, 1536, 0};
  wb.s[3]  = {W_rx, bWr,   n4x, 7, 1536, 1024};
  wb.s[4]  = {W_zh, bWz,   n4h, 8, 1536, 0};
  wb.s[5]  = {W_zx, bWz,   n4x, 7, 1536, 1024};
  wb.s[6]  = {WTh,  bWT,   n4h, 8, 2560, 0};
  wb.s[7]  = {WTx,  bWT,   n4x, 7, 2560, 1024};
  wb.s[8]  = {WTs,  bWT,   n4h, 8, 2560, 1536};
  wb.s[9]  = {W_h,  bWh,   n4h, 8, 1536, 0};
  wb.s[10] = {W_x,  bWh,   n4x, 7, 1536, 1024};
  conv_w<<<dim3(512, 11), 256, 0, stream>>>(wb);

  // Phase 1 (fused): s -> Ab cols 1536:2560 ; r*h -> RH ; z -> Zb
  // (readers touch Ab cols 0:1536 only -> col-disjoint from the s writes)
  gemm8<0, 12><<<dim3(768), 512, 0, stream>>>(
      Ab, LDA, bWsrz, 1536, 24, b_s, b_r, b_z,
      delta, W_st, h_prev, (void*)(Ab + 1536), LDA, (void*)RH, (void*)Zb);
  // Phase 2: htilde = tanh([r*h|x] @ [W_h|W_x]^T + b) -> HTb (alias-free)
  gemm8<3, 4><<<dim3(256), 512, 0, stream>>>(
      RH, LDR, bWh, 1536, 24, b_, nullptr, nullptr,
      nullptr, nullptr, nullptr, (void*)HTb, DH, nullptr, nullptr);
  // Phase 3: T gate ([h|x|s], K=2560) + final combine -> d_out (f32)
  gemm8<4, 4><<<dim3(256), 512, 0, stream>>>(
      Ab, LDA, bWT, 2560, 40, b_T, nullptr, nullptr,
      h_prev, Zb, HTb, (void*)out, DH, nullptr, nullptr);
}

// Round 9
// 641.967 us; speedup vs baseline: 1.1981x; 1.1981x over previous
//
#include <hip/hip_runtime.h>
#include <stdint.h>

#define AS1 __attribute__((address_space(1)))
#define AS3 __attribute__((address_space(3)))

typedef unsigned short US;
typedef __bf16 bf16x8 __attribute__((ext_vector_type(8)));
typedef float f32x4 __attribute__((ext_vector_type(4)));

static constexpr int Bsz = 16384;
static constexpr int DIN = 512;
static constexpr int DH  = 1024;
static constexpr int LDA = 2560;   // Ab row: [h(1024) | x(512) | s(1024)]
static constexpr int LDR = 1536;   // RH row: [r*h(1024) | x(512)]

__device__ __forceinline__ US f2bf(float f) {
  unsigned u = __float_as_uint(f);
  u += 0x7fffu + ((u >> 16) & 1u);          // RNE
  return (US)(u >> 16);
}
__device__ __forceinline__ float bf2f(US u) { return __uint_as_float(((unsigned)u) << 16); }
__device__ __forceinline__ float sigm(float x) { return 1.f / (1.f + __expf(-x)); }
__device__ __forceinline__ float tanh_f(float x) { return 1.f - 2.f / (1.f + __expf(2.f * x)); }

// ---------- convert kernels ----------
__global__ void pack_A(const float* __restrict__ h, const float* __restrict__ x,
                       US* __restrict__ Ab, US* __restrict__ RHx) {
  const int total = Bsz * 384;              // 1536 cols / 4 per item
  for (int idx = blockIdx.x * blockDim.x + threadIdx.x; idx < total;
       idx += gridDim.x * blockDim.x) {
    int row = idx / 384;
    int c = (idx - row * 384) * 4;
    const float* src = (c < DH) ? (h + (size_t)row * DH + c)
                                : (x + (size_t)row * DIN + (c - DH));
    float4 v = *(const float4*)src;
    ushort4 o;
    o.x = f2bf(v.x); o.y = f2bf(v.y); o.z = f2bf(v.z); o.w = f2bf(v.w);
    *(ushort4*)(Ab + (size_t)row * LDA + c) = o;
    if (c >= DH) *(ushort4*)(RHx + (size_t)row * LDR + c) = o;
  }
}

struct WSlot { const float* src; US* dst; int n4; int ksh; int ld; int co; };
struct WBatch { WSlot s[11]; };
__global__ void conv_w(WBatch b) {
  WSlot sl = b.s[blockIdx.y];   // uniform per block
  const int mask = (1 << sl.ksh) - 1;
  for (int i = blockIdx.x * blockDim.x + threadIdx.x; i < sl.n4;
       i += gridDim.x * blockDim.x) {
    float4 v = *(const float4*)(sl.src + (size_t)i * 4);
    ushort4 o;
    o.x = f2bf(v.x); o.y = f2bf(v.y); o.z = f2bf(v.z); o.w = f2bf(v.w);
    int r = i >> sl.ksh;
    int cc = (i & mask) * 4;
    *(ushort4*)(sl.dst + (size_t)r * sl.ld + sl.co + cc) = o;
  }
}

// ---------- 128x128 GEMM, dbuf 64KB LDS -> 2 blocks/CU, fused epilogue ------
// R8 post-mortem: all 256²/128KB-LDS variants have exactly 1 block/CU; fixed
// per-block overhead b≈35µs (prologue latency + barrier drains + epilogue)
// is unhidable. This kernel returns to R0's verified 128² machinery (swizzle,
// staging, reads, epilogue) + double-buffered LDS (64KB -> 2 blocks/CU; the
// sibling block covers barrier/drain stalls, m114 mechanism) + prefetch
// issued BEFORE compute (~1200cyc self-cover > 900cyc HBM latency).
// Race-freedom: STAGE targets buf^1; every wave's reads of buf^1 retired
// before the previous __syncthreads() (lgkm drained there), and the stage is
// issued only after that barrier. Simple __syncthreads() per tile; its drain
// residual is covered by the co-resident block.
//
// EPI: 0=s(tanh,+delta*wst)  1=r(sigm*h_prev)  2=z(sigm)  3=ht(tanh)
//      4=T(sigm; h_t=(1-z)(T*h)+z*ht -> f32)
template <int EPI>
__global__ __launch_bounds__(256) void gemm_ep(
    const US* __restrict__ A, int lda,
    const US* __restrict__ W, int ldw, int nt,
    const float* __restrict__ bias,
    const void* aux0, const void* aux1, const void* aux2,
    void* outp, int ldo) {
  __shared__ __align__(16) US As[2][128 * 64];
  __shared__ __align__(16) US Bs[2][128 * 64];

  const int tid  = threadIdx.x;
  const int lane = tid & 63;
  const int w    = tid >> 6;

  // XCD swizzle (R0-verified): XCD c owns m-slab [c*16, c*16+16), n fastest
  // -> the 8 n-peers of an m-block are co-resident on one XCD L2.
  const int p = blockIdx.x;
  const int c = p & 7, q = p >> 3;
  const int nIdx = q & 7;                 // 8 n-blocks (N=1024)
  const int mIdx = c * 16 + (q >> 3);     // 128 m-blocks
  const int mBase = mIdx * 128;
  const int nBase = nIdx * 128;

  f32x4 acc[4][4];
#pragma unroll
  for (int i = 0; i < 4; i++)
#pragma unroll
    for (int j = 0; j < 4; j++) acc[i][j] = f32x4{0.f, 0.f, 0.f, 0.f};

  // XOR swizzle (R0-verified, 0 bank conflicts): LDS(m,cc) = G(m, cc^(m&7));
  // linear LDS dest for global_load_lds, pre-swizzled global source.
  const int rowL = w * 32 + (lane >> 3);
  const int scc  = (lane & 7) ^ ((lane >> 3) & 7);
  const int gOff = scc * 8;
  const int wm = (w & 1) * 64, wn = (w >> 1) * 64;
  const int quad = lane >> 4, l15 = lane & 15;
  const int sw = l15 & 7;

  const US* gaBase = A + (size_t)(mBase + rowL) * lda + gOff;
  const US* gwBase = W + (size_t)(nBase + rowL) * ldw + gOff;
  const size_t a8 = (size_t)8 * lda, w8 = (size_t)8 * ldw;

#define STAGE(d, co)                                                             \
  { const US* ga = gaBase + (co);                                                \
    const US* gw = gwBase + (co);                                                \
    _Pragma("unroll")                                                            \
    for (int i = 0; i < 4; i++) {                                                \
      __builtin_amdgcn_global_load_lds((AS1 const void*)(ga + i * a8),           \
          (AS3 void*)&As[d][(w * 32 + i * 8) * 64], 16, 0, 0);                   \
      __builtin_amdgcn_global_load_lds((AS1 const void*)(gw + i * w8),           \
          (AS3 void*)&Bs[d][(w * 32 + i * 8) * 64], 16, 0, 0);                   \
    } }

#define COMPUTE(d)                                                               \
  { _Pragma("unroll")                                                            \
    for (int ks = 0; ks < 2; ++ks) {                                             \
      bf16x8 af[4], bw[4];                                                       \
      _Pragma("unroll")                                                          \
      for (int i = 0; i < 4; i++)                                                \
        af[i] = *(const bf16x8*)&As[d][(wm + i * 16 + l15) * 64 +                \
                                       (((ks * 4 + quad) ^ sw) * 8)];            \
      _Pragma("unroll")                                                          \
      for (int j = 0; j < 4; j++)                                                \
        bw[j] = *(const bf16x8*)&Bs[d][(wn + j * 16 + l15) * 64 +                \
                                       (((ks * 4 + quad) ^ sw) * 8)];            \
      _Pragma("unroll")                                                          \
      for (int i = 0; i < 4; i++)                                                \
        _Pragma("unroll")                                                        \
        for (int j = 0; j < 4; j++)                                              \
          acc[i][j] = __builtin_amdgcn_mfma_f32_16x16x32_bf16(af[i], bw[j],      \
                                                              acc[i][j], 0, 0, 0);\
    } }

  // ---- prologue: stage tile 0 into buf 0 ----
  STAGE(0, 0);
  __syncthreads();

  int cur = 0;
  for (int t = 0; t < nt; ++t, cur ^= 1) {
    if (t + 1 < nt) STAGE(cur ^ 1, (t + 1) * 64);   // prefetch BEFORE compute
    COMPUTE(cur);
    __syncthreads();    // drains stage (vmcnt) + lds reads; sibling block
                        // on the CU covers this stall (2 blocks/CU)
  }
#undef STAGE
#undef COMPUTE

  // epilogue: row = mBase+wm+i*16+quad*4+r ; col = nBase+wn+j*16+l15
#pragma unroll
  for (int i = 0; i < 4; i++) {
#pragma unroll
    for (int j = 0; j < 4; j++) {
      const int col = nBase + wn + j * 16 + l15;
      const float bv = bias[col];
#pragma unroll
      for (int r = 0; r < 4; r++) {
        const int row = mBase + wm + i * 16 + quad * 4 + r;
        float v = acc[i][j][r] + bv;
        if constexpr (EPI == 0) {
          const float* delta = (const float*)aux0;
          const float* wst   = (const float*)aux1;
          v += delta[row] * wst[col];
          ((US*)outp)[(size_t)row * ldo + col] = f2bf(tanh_f(v));
        } else if constexpr (EPI == 1) {
          const float* hp = (const float*)aux0;   // pristine f32 h_prev
          float rr = sigm(v);
          ((US*)outp)[(size_t)row * ldo + col] =
              f2bf(rr * hp[(size_t)row * DH + col]);
        } else if constexpr (EPI == 2) {
          ((US*)outp)[(size_t)row * ldo + col] = f2bf(sigm(v));
        } else if constexpr (EPI == 3) {
          ((US*)outp)[(size_t)row * ldo + col] = f2bf(tanh_f(v));
        } else {
          const float* hp = (const float*)aux0;   // pristine f32 h_prev
          const US* Zp = (const US*)aux1;         // z, stride DH
          const US* Hp = (const US*)aux2;         // htilde, stride DH
          float T = sigm(v);
          size_t o = (size_t)row * DH + col;
          float z = bf2f(Zp[o]), ht = bf2f(Hp[o]);
          float h = hp[o];
          ((float*)outp)[(size_t)row * ldo + col] = (1.f - z) * (T * h) + z * ht;
        }
      }
    }
  }
}

extern "C" void kernel_launch(void* const* d_in, const int* in_sizes, int n_in,
                              void* d_out, int out_size, void* d_ws, size_t ws_size,
                              hipStream_t stream) {
  const float* x_t   = (const float*)d_in[0];
  const float* delta = (const float*)d_in[1];
  const float* h_prev= (const float*)d_in[2];
  const float* W_sh  = (const float*)d_in[3];
  const float* W_sx  = (const float*)d_in[4];
  const float* W_st  = (const float*)d_in[5];
  const float* b_s   = (const float*)d_in[6];
  const float* WTh   = (const float*)d_in[7];
  const float* WTx   = (const float*)d_in[8];
  const float* WTs   = (const float*)d_in[9];
  const float* b_T   = (const float*)d_in[10];
  const float* W_rh  = (const float*)d_in[11];
  const float* W_rx  = (const float*)d_in[12];
  const float* b_r   = (const float*)d_in[13];
  const float* W_zh  = (const float*)d_in[14];
  const float* W_zx  = (const float*)d_in[15];
  const float* b_z   = (const float*)d_in[16];
  const float* W_h   = (const float*)d_in[17];
  const float* W_x   = (const float*)d_in[18];
  const float* b_    = (const float*)d_in[19];
  float* out = (float*)d_out;

  char* ws = (char*)d_ws;
  US* Ab  = (US*)ws;              size_t off = (size_t)Bsz * LDA * 2;   // 80MB
  US* RH  = (US*)(ws + off);      off += (size_t)Bsz * LDR * 2;         // 48MB
  US* Zb  = (US*)(ws + off);      off += (size_t)Bsz * DH * 2;          // 32MB
  US* HTb = (US*)(ws + off);      off += (size_t)Bsz * DH * 2;          // 32MB
  US* bWsrz = (US*)(ws + off);    off += (size_t)3072 * 1536 * 2;       // 9MB
  US* bWT   = (US*)(ws + off);    off += (size_t)DH * 2560 * 2;         // 5MB
  US* bWh   = (US*)(ws + off);    off += (size_t)DH * 1536 * 2;         // 3MB

  // Stage 0: convert
  pack_A<<<dim3(8192), 256, 0, stream>>>(h_prev, x_t, Ab, RH);
  WBatch wb;
  const int n4h = DH * DH / 4, n4x = DH * DIN / 4;   // ksh: 1024->8, 512->7
  US* bWr = bWsrz + (size_t)1024 * 1536;
  US* bWz = bWsrz + (size_t)2048 * 1536;
  wb.s[0]  = {W_sh, bWsrz, n4h, 8, 1536, 0};
  wb.s[1]  = {W_sx, bWsrz, n4x, 7, 1536, 1024};
  wb.s[2]  = {W_rh, bWr,   n4h, 8, 1536, 0};
  wb.s[3]  = {W_rx, bWr,   n4x, 7, 1536, 1024};
  wb.s[4]  = {W_zh, bWz,   n4h, 8, 1536, 0};
  wb.s[5]  = {W_zx, bWz,   n4x, 7, 1536, 1024};
  wb.s[6]  = {WTh,  bWT,   n4h, 8, 2560, 0};
  wb.s[7]  = {WTx,  bWT,   n4x, 7, 2560, 1024};
  wb.s[8]  = {WTs,  bWT,   n4h, 8, 2560, 1536};
  wb.s[9]  = {W_h,  bWh,   n4h, 8, 1536, 0};
  wb.s[10] = {W_x,  bWh,   n4x, 7, 1536, 1024};
  conv_w<<<dim3(512, 11), 256, 0, stream>>>(wb);

  const dim3 grid(1024);   // 8 n-blocks x 128 m-blocks; ~2 blocks/CU resident

  // Phase 1: s -> Ab cols 1536:2560 (reads cols 0:1536 only; col-disjoint)
  gemm_ep<0><<<grid, 256, 0, stream>>>(Ab, LDA, bWsrz, 1536, 24, b_s,
                                       delta, W_st, nullptr,
                                       (void*)(Ab + 1536), LDA);
  // r*h -> RH cols 0:1024
  gemm_ep<1><<<grid, 256, 0, stream>>>(Ab, LDA, bWr, 1536, 24, b_r,
                                       h_prev, nullptr, nullptr,
                                       (void*)RH, LDR);
  // z -> Zb
  gemm_ep<2><<<grid, 256, 0, stream>>>(Ab, LDA, bWz, 1536, 24, b_z,
                                       nullptr, nullptr, nullptr,
                                       (void*)Zb, DH);
  // Phase 2: htilde = tanh([r*h|x] @ [W_h|W_x]^T + b) -> HTb (alias-free)
  gemm_ep<3><<<grid, 256, 0, stream>>>(RH, LDR, bWh, 1536, 24, b_,
                                       nullptr, nullptr, nullptr,
                                       (void*)HTb, DH);
  // Phase 3: T gate ([h|x|s], K=2560) + final combine -> d_out (f32)
  gemm_ep<4><<<grid, 256, 0, stream>>>(Ab, LDA, bWT, 2560, 40, b_T,
                                       h_prev, Zb, HTb,
                                       (void*)out, DH);
}